// Round 1
// baseline (9718.957 us; speedup 1.0000x reference)
//
#include <hip/hip_runtime.h>

#define N_LAYERS 1000
#define DD 100
#define DOUT 10
#define TM 128
#define WCHUNK 32768            // bytes per layer per split: 128 rows * 128 k * 2B
#define SMEM_BYTES 131072       // act_hi 32K | act_lo 32K | Whi 32K | Wlo 32K

typedef short s8v __attribute__((ext_vector_type(8)));
typedef short s4v __attribute__((ext_vector_type(4)));
typedef float f16v __attribute__((ext_vector_type(16)));

__device__ __forceinline__ unsigned short f2bf(float f) {
  unsigned u = __float_as_uint(f);
  u += 0x7FFFu + ((u >> 16) & 1u);   // RNE to bf16
  return (unsigned short)(u >> 16);
}
__device__ __forceinline__ float bf2f(unsigned short h) {
  return __uint_as_float(((unsigned)h) << 16);
}
// [row][k] bf16, 256B row stride, XOR-swizzle bits 4-6 by row&7 (bank-conflict-free b128)
__device__ __forceinline__ int swz(int row, int kbyte) {
  return (row * 256 + kbyte) ^ ((row & 7) << 4);
}

// ---------------- prologue: pre-split W (f32) -> swizzled bf16 hi/lo, padded 128x128 ----------------
__global__ __launch_bounds__(256)
void presplit_kernel(const float* __restrict__ W, char* __restrict__ hi_g, char* __restrict__ lo_g) {
  int idx = blockIdx.x * 256 + threadIdx.x;
  if (idx >= N_LAYERS * 128 * 16) return;
  int L = idx >> 11;          // / (128*16)
  int rem = idx & 2047;
  int n = rem >> 4;           // out-channel row 0..127
  int kb = rem & 15;          // 16B block of 8 k
  s8v hv, lv;
#pragma unroll
  for (int j = 0; j < 8; ++j) {
    int k = kb * 8 + j;
    float v = (n < DD && k < DD) ? W[(size_t)L * (DD * DD) + n * DD + k] : 0.0f;
    unsigned short h = f2bf(v);
    float r = v - bf2f(h);
    hv[j] = (short)h;
    lv[j] = (short)f2bf(r);
  }
  size_t off = (size_t)L * WCHUNK + (size_t)swz(n, kb * 16);
  *(s8v*)(hi_g + off) = hv;
  *(s8v*)(lo_g + off) = lv;
}

// ---------------- staging helpers ----------------
__device__ __forceinline__ void stage_pre(char* dst, const char* src, int tid) {
  const s8v* s = (const s8v*)src;
  s8v* d = (s8v*)dst;
#pragma unroll
  for (int i = 0; i < 8; ++i) d[tid + 256 * i] = s[tid + 256 * i];   // 2048 * 16B = 32KB
}

// fallback: convert f32 weights on the fly (pads must be pre-zeroed once)
__device__ __forceinline__ void stage_f32(char* dst, const float* __restrict__ wsrc, int sel, int tid) {
  for (int idx = tid; idx < 100 * 13; idx += 256) {
    int n = idx / 13;
    int kb = idx - n * 13;
    s8v ov;
#pragma unroll
    for (int j = 0; j < 8; ++j) {
      int k = kb * 8 + j;
      float v = (k < DD) ? wsrc[n * DD + k] : 0.0f;
      unsigned short h = f2bf(v);
      if (sel == 0) ov[j] = (short)h;
      else { float r = v - bf2f(h); ov[j] = (short)f2bf(r); }
    }
    *(s8v*)(dst + swz(n, kb * 16)) = ov;
  }
}

// ---------------- main persistent kernel ----------------
template <int PRESPLIT>
__global__ __launch_bounds__(256, 1)
void resnet_main(const float* __restrict__ x_g, const float* __restrict__ W_g,
                 const float* __restrict__ b_g, const float* __restrict__ Wf_g,
                 const float* __restrict__ bf_g, float* __restrict__ out_g,
                 const char* __restrict__ whi_g, const char* __restrict__ wlo_g) {
  extern __shared__ char smem[];
  char* ACT_H = smem;
  char* ACT_L = smem + 32768;
  char* WB0 = smem + 65536;   // W hi
  char* WB1 = smem + 98304;   // W lo

  const int tid = threadIdx.x;
  const int lane = tid & 63;
  const int wv = tid >> 6;
  const int l31 = lane & 31;
  const int lhi = lane >> 5;
  const int mt0 = (wv & 1) * 2;   // this wave's m-tile pair
  const int nt0 = (wv >> 1) * 2;  // this wave's n-tile pair
  const size_t mbase = (size_t)blockIdx.x * TM;

  if (!PRESPLIT) {            // zero W buffers once (pads stay zero forever)
    s8v z;
#pragma unroll
    for (int j = 0; j < 8; ++j) z[j] = 0;
    s8v* wz = (s8v*)WB0;
    for (int i = tid; i < 4096; i += 256) wz[i] = z;
  }

  // ---- initial activation staging: act = split(x), k-pads zero ----
  for (int idx = tid; idx < 128 * 16; idx += 256) {
    int m = idx >> 4, kb = idx & 15;
    s8v hv, lv;
#pragma unroll
    for (int j = 0; j < 8; ++j) {
      int k = kb * 8 + j;
      float v = (k < DD) ? x_g[(mbase + m) * DD + k] : 0.0f;
      unsigned short h = f2bf(v);
      float r = v - bf2f(h);
      hv[j] = (short)h;
      lv[j] = (short)f2bf(r);
    }
    int a = swz(m, kb * 16);
    *(s8v*)(ACT_H + a) = hv;
    *(s8v*)(ACT_L + a) = lv;
  }

  // ---- residual x in registers, C-fragment layout (lane=batch col, regs=channel rows) ----
  f16v xr[2][2];
#pragma unroll
  for (int ni = 0; ni < 2; ++ni)
#pragma unroll
    for (int mi = 0; mi < 2; ++mi)
#pragma unroll
      for (int r = 0; r < 16; ++r) {
        int n = (nt0 + ni) * 32 + (r & 3) + 8 * (r >> 2) + 4 * lhi;
        int m = (mt0 + mi) * 32 + l31;
        xr[ni][mi][r] = (n < DD) ? x_g[(mbase + m) * DD + n] : 0.0f;
      }

  // ---- stage W_hi(0) ----
  if (PRESPLIT) stage_pre(WB0, whi_g, tid);
  else          stage_f32(WB0, W_g, 0, tid);
  __syncthreads();

  f16v acc[2][2];
  for (int L = 0; L < N_LAYERS; ++L) {
#pragma unroll
    for (int ni = 0; ni < 2; ++ni)
#pragma unroll
      for (int mi = 0; mi < 2; ++mi)
#pragma unroll
        for (int r = 0; r < 16; ++r) acc[ni][mi][r] = 0.0f;

    // stage W_lo(L) into WB1 while computing phase A out of WB0
    if (PRESPLIT) stage_pre(WB1, wlo_g + (size_t)L * WCHUNK, tid);
    else          stage_f32(WB1, W_g + (size_t)L * (DD * DD), 1, tid);

    // ---- phase A: acc += Whi*act_hi + Whi*act_lo ----
#pragma unroll
    for (int ks = 0; ks < 7; ++ks) {
      int kbyte = ks * 32 + lhi * 16;
      s8v wf0 = *(const s8v*)(WB0 + swz(nt0 * 32 + l31, kbyte));
      s8v wf1 = *(const s8v*)(WB0 + swz((nt0 + 1) * 32 + l31, kbyte));
      int a0 = swz(mt0 * 32 + l31, kbyte);
      int a1 = swz((mt0 + 1) * 32 + l31, kbyte);
      s8v ah0 = *(const s8v*)(ACT_H + a0);
      s8v ah1 = *(const s8v*)(ACT_H + a1);
      s8v al0 = *(const s8v*)(ACT_L + a0);
      s8v al1 = *(const s8v*)(ACT_L + a1);
      acc[0][0] = __builtin_amdgcn_mfma_f32_32x32x16_bf16(wf0, ah0, acc[0][0], 0, 0, 0);
      acc[0][1] = __builtin_amdgcn_mfma_f32_32x32x16_bf16(wf0, ah1, acc[0][1], 0, 0, 0);
      acc[1][0] = __builtin_amdgcn_mfma_f32_32x32x16_bf16(wf1, ah0, acc[1][0], 0, 0, 0);
      acc[1][1] = __builtin_amdgcn_mfma_f32_32x32x16_bf16(wf1, ah1, acc[1][1], 0, 0, 0);
      acc[0][0] = __builtin_amdgcn_mfma_f32_32x32x16_bf16(wf0, al0, acc[0][0], 0, 0, 0);
      acc[0][1] = __builtin_amdgcn_mfma_f32_32x32x16_bf16(wf0, al1, acc[0][1], 0, 0, 0);
      acc[1][0] = __builtin_amdgcn_mfma_f32_32x32x16_bf16(wf1, al0, acc[1][0], 0, 0, 0);
      acc[1][1] = __builtin_amdgcn_mfma_f32_32x32x16_bf16(wf1, al1, acc[1][1], 0, 0, 0);
    }
    __syncthreads();

    // stage W_hi(L+1) into WB0 while computing phase B out of WB1
    if (L + 1 < N_LAYERS) {
      if (PRESPLIT) stage_pre(WB0, whi_g + (size_t)(L + 1) * WCHUNK, tid);
      else          stage_f32(WB0, W_g + (size_t)(L + 1) * (DD * DD), 0, tid);
    }

    // bias prefetch (reg layout mirrors C-fragment rows)
    float bv[2][16];
#pragma unroll
    for (int ni = 0; ni < 2; ++ni)
#pragma unroll
      for (int r = 0; r < 16; ++r) {
        int n = (nt0 + ni) * 32 + (r & 3) + 8 * (r >> 2) + 4 * lhi;
        bv[ni][r] = (n < DD) ? b_g[(size_t)L * DD + n] : 0.0f;
      }

    // ---- phase B: acc += Wlo*act_hi ----
#pragma unroll
    for (int ks = 0; ks < 7; ++ks) {
      int kbyte = ks * 32 + lhi * 16;
      s8v wf0 = *(const s8v*)(WB1 + swz(nt0 * 32 + l31, kbyte));
      s8v wf1 = *(const s8v*)(WB1 + swz((nt0 + 1) * 32 + l31, kbyte));
      s8v ah0 = *(const s8v*)(ACT_H + swz(mt0 * 32 + l31, kbyte));
      s8v ah1 = *(const s8v*)(ACT_H + swz((mt0 + 1) * 32 + l31, kbyte));
      acc[0][0] = __builtin_amdgcn_mfma_f32_32x32x16_bf16(wf0, ah0, acc[0][0], 0, 0, 0);
      acc[0][1] = __builtin_amdgcn_mfma_f32_32x32x16_bf16(wf0, ah1, acc[0][1], 0, 0, 0);
      acc[1][0] = __builtin_amdgcn_mfma_f32_32x32x16_bf16(wf1, ah0, acc[1][0], 0, 0, 0);
      acc[1][1] = __builtin_amdgcn_mfma_f32_32x32x16_bf16(wf1, ah1, acc[1][1], 0, 0, 0);
    }
    __syncthreads();

    // ---- epilogue: bias + relu (+ residual at block end), split, write act ----
    const bool bend = ((L % 10) == 9);
#pragma unroll
    for (int ni = 0; ni < 2; ++ni)
#pragma unroll
      for (int mi = 0; mi < 2; ++mi) {
        int m = (mt0 + mi) * 32 + l31;
#pragma unroll
        for (int q = 0; q < 4; ++q) {
          s4v hq, lq;
#pragma unroll
          for (int j = 0; j < 4; ++j) {
            int r = q * 4 + j;
            float z = fmaxf(acc[ni][mi][r] + bv[ni][r], 0.0f);
            float o;
            if (bend) { float nx = xr[ni][mi][r] + z; xr[ni][mi][r] = nx; o = nx; }
            else o = z;
            unsigned short h = f2bf(o);
            float rr = o - bf2f(h);
            hq[j] = (short)h;
            lq[j] = (short)f2bf(rr);
          }
          int n0 = (nt0 + ni) * 32 + 8 * q + 4 * lhi;   // 4 consecutive channels -> b64
          int a = swz(m, n0 * 2);
          *(s4v*)(ACT_H + a) = hq;
          *(s4v*)(ACT_L + a) = lq;
        }
      }
    __syncthreads();
  }

  // ---- final projection: out = x @ Wf^T + bf (x == act_hi+act_lo) ----
  if (tid < TM) {
    int m = tid;
    float xv[104];
#pragma unroll
    for (int kb = 0; kb < 13; ++kb) {
      int a = swz(m, kb * 16);
      s8v h = *(const s8v*)(ACT_H + a);
      s8v l = *(const s8v*)(ACT_L + a);
#pragma unroll
      for (int j = 0; j < 8; ++j)
        xv[kb * 8 + j] = bf2f((unsigned short)h[j]) + bf2f((unsigned short)l[j]);
    }
#pragma unroll
    for (int o = 0; o < DOUT; ++o) {
      float s = bf_g[o];
#pragma unroll
      for (int k = 0; k < DD; ++k) s += xv[k] * Wf_g[o * DD + k];
      out_g[(mbase + m) * DOUT + o] = s;
    }
  }
}

extern "C" void kernel_launch(void* const* d_in, const int* in_sizes, int n_in,
                              void* d_out, int out_size, void* d_ws, size_t ws_size,
                              hipStream_t stream) {
  const float* x = (const float*)d_in[0];
  const float* W = (const float*)d_in[1];
  const float* b = (const float*)d_in[2];
  const float* Wf = (const float*)d_in[3];
  const float* bf = (const float*)d_in[4];
  float* out = (float*)d_out;

  const size_t need = (size_t)2 * N_LAYERS * WCHUNK;   // 62.5 MB
  if (ws_size >= need) {
    char* whi = (char*)d_ws;
    char* wlo = whi + (size_t)N_LAYERS * WCHUNK;
    presplit_kernel<<<8000, 256, 0, stream>>>(W, whi, wlo);
    (void)hipFuncSetAttribute(reinterpret_cast<const void*>(resnet_main<1>),
                              hipFuncAttributeMaxDynamicSharedMemorySize, SMEM_BYTES);
    resnet_main<1><<<65536 / TM, 256, SMEM_BYTES, stream>>>(x, W, b, Wf, bf, out, whi, wlo);
  } else {
    (void)hipFuncSetAttribute(reinterpret_cast<const void*>(resnet_main<0>),
                              hipFuncAttributeMaxDynamicSharedMemorySize, SMEM_BYTES);
    resnet_main<0><<<65536 / TM, 256, SMEM_BYTES, stream>>>(x, W, b, Wf, bf, out, nullptr, nullptr);
  }
}

// Round 2
// 6658.443 us; speedup vs baseline: 1.4596x; 1.4596x over previous
//
#include <hip/hip_runtime.h>

#define N_LAYERS 1000
#define DD 100
#define DOUT 10
#define TM 128
#define LCHUNK 14336            // bytes per (layer,g) per split: 7ks * 2f * 64lane * 16B
#define SMEM_BYTES 65536        // act_hi 32K | act_lo 32K

typedef short s8v __attribute__((ext_vector_type(8)));
typedef short s4v __attribute__((ext_vector_type(4)));
typedef float f16v __attribute__((ext_vector_type(16)));

__device__ __forceinline__ unsigned short f2bf(float f) {
  unsigned u = __float_as_uint(f);
  u += 0x7FFFu + ((u >> 16) & 1u);   // RNE to bf16
  return (unsigned short)(u >> 16);
}
__device__ __forceinline__ float bf2f(unsigned short h) {
  return __uint_as_float(((unsigned)h) << 16);
}
// [row][k] bf16, 256B row stride, XOR-swizzle bits 4-6 by row&7 (bank-spread b128)
__device__ __forceinline__ int swz(int row, int kbyte) {
  return (row * 256 + kbyte) ^ ((row & 7) << 4);
}

// ---------------- prologue: W (f32) + bias -> lane-packed bf16 hi/lo fragments ----------------
// chunk id idx = (((L*2+g)*7+ks)*2+f)*64+lane ; 16B at idx*16.
// frag (g,ks,f,lane): n = g*64+f*32+(lane&31), k = ks*16+(lane>>5)*8+j ; k==100 holds bias.
__global__ __launch_bounds__(256)
void presplit_kernel(const float* __restrict__ W, const float* __restrict__ b,
                     char* __restrict__ hi_g, char* __restrict__ lo_g) {
  int idx = blockIdx.x * 256 + threadIdx.x;
  if (idx >= N_LAYERS * 2 * 7 * 2 * 64) return;
  int lane = idx & 63;
  int f = (idx >> 6) & 1;
  int r = idx >> 7;
  int ks = r % 7;
  int q = r / 7;
  int g = q & 1;
  int L = q >> 1;
  int n = g * 64 + f * 32 + (lane & 31);
  int k0 = ks * 16 + (lane >> 5) * 8;
  s8v hv, lv;
#pragma unroll
  for (int j = 0; j < 8; ++j) {
    int k = k0 + j;
    float v = 0.0f;
    if (n < DD) {
      if (k < DD) v = W[((size_t)L * DD + n) * DD + k];
      else if (k == DD) v = b[(size_t)L * DD + n];
    }
    unsigned short h = f2bf(v);
    float rr = v - bf2f(h);
    hv[j] = (short)h;
    lv[j] = (short)f2bf(rr);
  }
  *(s8v*)(hi_g + (size_t)idx * 16) = hv;
  *(s8v*)(lo_g + (size_t)idx * 16) = lv;
}

// ---------------- W fragment load: packed (fast) or raw-f32 gather (fallback) ----------------
template <int PRE>
__device__ __forceinline__ void wload(s8v& h0, s8v& h1, s8v& l0, s8v& l1,
                                      int L, int ks, int g, int lane, int l31, int lhi,
                                      const char* __restrict__ whi_g,
                                      const char* __restrict__ wlo_g,
                                      const float* __restrict__ W_g,
                                      const float* __restrict__ b_g) {
  if (PRE) {
    size_t base = (size_t)(L * 2 + g) * LCHUNK + (size_t)ks * 2048 + (size_t)lane * 16;
    h0 = *(const s8v*)(whi_g + base);
    h1 = *(const s8v*)(whi_g + base + 1024);
    l0 = *(const s8v*)(wlo_g + base);
    l1 = *(const s8v*)(wlo_g + base + 1024);
  } else {
    int k0 = ks * 16 + lhi * 8;
#pragma unroll
    for (int f = 0; f < 2; ++f) {
      int n = g * 64 + f * 32 + l31;
      s8v hv, lv;
#pragma unroll
      for (int j = 0; j < 8; ++j) {
        int k = k0 + j;
        float v = 0.0f;
        if (n < DD) {
          if (k < DD) v = W_g[((size_t)L * DD + n) * DD + k];
          else if (k == DD) v = b_g[(size_t)L * DD + n];
        }
        unsigned short h = f2bf(v);
        float rr = v - bf2f(h);
        hv[j] = (short)h;
        lv[j] = (short)f2bf(rr);
      }
      if (f == 0) { h0 = hv; l0 = lv; }
      else        { h1 = hv; l1 = lv; }
    }
  }
}

// ---------------- main persistent kernel: 512 wgs, 2 wgs/CU, W in regs, act in LDS ----------------
template <int PRE>
__global__ __launch_bounds__(256, 2)
void resnet_main(const float* __restrict__ x_g,
                 const float* __restrict__ W_g, const float* __restrict__ b_g,
                 const float* __restrict__ Wf_g, const float* __restrict__ bf_g,
                 float* __restrict__ out_g,
                 const char* __restrict__ whi_g, const char* __restrict__ wlo_g) {
  extern __shared__ char smem[];
  char* ACT_H = smem;
  char* ACT_L = smem + 32768;

  const int tid = threadIdx.x;
  const int lane = tid & 63;
  const int wv = tid >> 6;
  const int l31 = lane & 31;
  const int lhi = lane >> 5;
  const int mt0 = (wv & 1) * 2;   // wave's m-tile pair
  const int nt0 = (wv >> 1) * 2;  // wave's n-tile pair
  const int g = wv >> 1;          // W packed group index
  const size_t mbase = (size_t)blockIdx.x * TM;

  // ---- initial activation staging: split(x), k==100 -> 1.0 (bias column), k>100 -> 0 ----
  for (int idx = tid; idx < 128 * 16; idx += 256) {
    int m = idx >> 4, kb = idx & 15;
    s8v hv, lv;
#pragma unroll
    for (int j = 0; j < 8; ++j) {
      int k = kb * 8 + j;
      float v = (k < DD) ? x_g[(mbase + m) * DD + k] : (k == DD ? 1.0f : 0.0f);
      unsigned short h = f2bf(v);
      float rr = v - bf2f(h);
      hv[j] = (short)h;
      lv[j] = (short)f2bf(rr);
    }
    int a = swz(m, kb * 16);
    *(s8v*)(ACT_H + a) = hv;
    *(s8v*)(ACT_L + a) = lv;
  }

  // ---- residual x in registers, C-fragment layout ----
  f16v xr[2][2];
#pragma unroll
  for (int ni = 0; ni < 2; ++ni)
#pragma unroll
    for (int mi = 0; mi < 2; ++mi)
#pragma unroll
      for (int r = 0; r < 16; ++r) {
        int n = (nt0 + ni) * 32 + (r & 3) + 8 * (r >> 2) + 4 * lhi;
        int m = (mt0 + mi) * 32 + l31;
        xr[ni][mi][r] = (n < DD) ? x_g[(mbase + m) * DD + n] : 0.0f;
      }

  f16v zro;
#pragma unroll
  for (int r = 0; r < 16; ++r) zro[r] = 0.0f;

  // ---- W double-slot register pipeline: preload ks=0,1 of layer 0 ----
  s8v wh0[2], wh1[2], wl0[2], wl1[2];
  wload<PRE>(wh0[0], wh1[0], wl0[0], wl1[0], 0, 0, g, lane, l31, lhi, whi_g, wlo_g, W_g, b_g);
  wload<PRE>(wh0[1], wh1[1], wl0[1], wl1[1], 0, 1, g, lane, l31, lhi, whi_g, wlo_g, W_g, b_g);

  __syncthreads();

  const int arow0 = mt0 * 32 + l31;
  f16v acc[2][2];

  for (int L = 0; L < N_LAYERS; ++L) {
#pragma unroll
    for (int ks = 0; ks < 7; ++ks) {
      const int s = ks & 1;
      const int kb = ks * 32 + lhi * 16;
      const int a0 = swz(arow0, kb);
      const int a1 = swz(arow0 + 32, kb);
      s8v ah0 = *(const s8v*)(ACT_H + a0);
      s8v ah1 = *(const s8v*)(ACT_H + a1);
      s8v al0 = *(const s8v*)(ACT_L + a0);
      s8v al1 = *(const s8v*)(ACT_L + a1);
      if (ks == 0) {
        acc[0][0] = __builtin_amdgcn_mfma_f32_32x32x16_bf16(wh0[s], ah0, zro, 0, 0, 0);
        acc[0][1] = __builtin_amdgcn_mfma_f32_32x32x16_bf16(wh0[s], ah1, zro, 0, 0, 0);
        acc[1][0] = __builtin_amdgcn_mfma_f32_32x32x16_bf16(wh1[s], ah0, zro, 0, 0, 0);
        acc[1][1] = __builtin_amdgcn_mfma_f32_32x32x16_bf16(wh1[s], ah1, zro, 0, 0, 0);
      } else {
        acc[0][0] = __builtin_amdgcn_mfma_f32_32x32x16_bf16(wh0[s], ah0, acc[0][0], 0, 0, 0);
        acc[0][1] = __builtin_amdgcn_mfma_f32_32x32x16_bf16(wh0[s], ah1, acc[0][1], 0, 0, 0);
        acc[1][0] = __builtin_amdgcn_mfma_f32_32x32x16_bf16(wh1[s], ah0, acc[1][0], 0, 0, 0);
        acc[1][1] = __builtin_amdgcn_mfma_f32_32x32x16_bf16(wh1[s], ah1, acc[1][1], 0, 0, 0);
      }
      acc[0][0] = __builtin_amdgcn_mfma_f32_32x32x16_bf16(wh0[s], al0, acc[0][0], 0, 0, 0);
      acc[0][1] = __builtin_amdgcn_mfma_f32_32x32x16_bf16(wh0[s], al1, acc[0][1], 0, 0, 0);
      acc[1][0] = __builtin_amdgcn_mfma_f32_32x32x16_bf16(wh1[s], al0, acc[1][0], 0, 0, 0);
      acc[1][1] = __builtin_amdgcn_mfma_f32_32x32x16_bf16(wh1[s], al1, acc[1][1], 0, 0, 0);
      acc[0][0] = __builtin_amdgcn_mfma_f32_32x32x16_bf16(wl0[s], ah0, acc[0][0], 0, 0, 0);
      acc[0][1] = __builtin_amdgcn_mfma_f32_32x32x16_bf16(wl0[s], ah1, acc[0][1], 0, 0, 0);
      acc[1][0] = __builtin_amdgcn_mfma_f32_32x32x16_bf16(wl1[s], ah0, acc[1][0], 0, 0, 0);
      acc[1][1] = __builtin_amdgcn_mfma_f32_32x32x16_bf16(wl1[s], ah1, acc[1][1], 0, 0, 0);

      // depth-2 prefetch: slots self-consistent within a layer; cross-layer refill at ks==6
      if (ks < 5) {
        wload<PRE>(wh0[s], wh1[s], wl0[s], wl1[s], L, ks + 2, g, lane, l31, lhi, whi_g, wlo_g, W_g, b_g);
      } else if (ks == 6 && L + 1 < N_LAYERS) {
        wload<PRE>(wh0[0], wh1[0], wl0[0], wl1[0], L + 1, 0, g, lane, l31, lhi, whi_g, wlo_g, W_g, b_g);
        wload<PRE>(wh0[1], wh1[1], wl0[1], wl1[1], L + 1, 1, g, lane, l31, lhi, whi_g, wlo_g, W_g, b_g);
      }
    }

    __syncthreads();   // all act reads done before overwrite

    // ---- epilogue: relu (+residual at block end), bias came free via k=100; write act ----
    const bool bend = ((L % 10) == 9);
#pragma unroll
    for (int ni = 0; ni < 2; ++ni)
#pragma unroll
      for (int mi = 0; mi < 2; ++mi) {
        const int m = (mt0 + mi) * 32 + l31;
#pragma unroll
        for (int q = 0; q < 4; ++q) {
          const int n0 = (nt0 + ni) * 32 + 8 * q + 4 * lhi;
          s4v hq, lq;
          if (n0 == 100) {   // bias column: act[100] = 1.0, pads 101..103 = 0
            hq[0] = (short)0x3F80; hq[1] = 0; hq[2] = 0; hq[3] = 0;
            lq[0] = 0; lq[1] = 0; lq[2] = 0; lq[3] = 0;
          } else {
#pragma unroll
            for (int j = 0; j < 4; ++j) {
              const int r = q * 4 + j;
              float z = fmaxf(acc[ni][mi][r], 0.0f);
              float o;
              if (bend) { float nx = xr[ni][mi][r] + z; xr[ni][mi][r] = nx; o = nx; }
              else o = z;
              unsigned short h = f2bf(o);
              float rr = o - bf2f(h);
              hq[j] = (short)h;
              lq[j] = (short)f2bf(rr);
            }
          }
          const int a = swz(m, n0 * 2);
          *(s4v*)(ACT_H + a) = hq;
          *(s4v*)(ACT_L + a) = lq;
        }
      }
    __syncthreads();   // writes visible for next layer
  }

  // ---- final projection: out = act @ Wf^T + bf ----
  if (tid < TM) {
    int m = tid;
    float xv[104];
#pragma unroll
    for (int kb = 0; kb < 13; ++kb) {
      int a = swz(m, kb * 16);
      s8v h = *(const s8v*)(ACT_H + a);
      s8v l = *(const s8v*)(ACT_L + a);
#pragma unroll
      for (int j = 0; j < 8; ++j)
        xv[kb * 8 + j] = bf2f((unsigned short)h[j]) + bf2f((unsigned short)l[j]);
    }
#pragma unroll
    for (int o = 0; o < DOUT; ++o) {
      float s = bf_g[o];
#pragma unroll
      for (int k = 0; k < DD; ++k) s += xv[k] * Wf_g[o * DD + k];
      out_g[(mbase + m) * DOUT + o] = s;
    }
  }
}

extern "C" void kernel_launch(void* const* d_in, const int* in_sizes, int n_in,
                              void* d_out, int out_size, void* d_ws, size_t ws_size,
                              hipStream_t stream) {
  const float* x = (const float*)d_in[0];
  const float* W = (const float*)d_in[1];
  const float* b = (const float*)d_in[2];
  const float* Wf = (const float*)d_in[3];
  const float* bf = (const float*)d_in[4];
  float* out = (float*)d_out;

  const size_t split_bytes = (size_t)N_LAYERS * 2 * LCHUNK;   // 28.672 MB per split
  const size_t need = 2 * split_bytes;                        // 57.344 MB
  if (ws_size >= need) {
    char* whi = (char*)d_ws;
    char* wlo = whi + split_bytes;
    const int chunks = N_LAYERS * 2 * 7 * 2 * 64;             // 1,792,000
    presplit_kernel<<<(chunks + 255) / 256, 256, 0, stream>>>(W, b, whi, wlo);
    (void)hipFuncSetAttribute(reinterpret_cast<const void*>(resnet_main<1>),
                              hipFuncAttributeMaxDynamicSharedMemorySize, SMEM_BYTES);
    resnet_main<1><<<65536 / TM, 256, SMEM_BYTES, stream>>>(x, W, b, Wf, bf, out, whi, wlo);
  } else {
    (void)hipFuncSetAttribute(reinterpret_cast<const void*>(resnet_main<0>),
                              hipFuncAttributeMaxDynamicSharedMemorySize, SMEM_BYTES);
    resnet_main<0><<<65536 / TM, 256, SMEM_BYTES, stream>>>(x, W, b, Wf, bf, out, nullptr, nullptr);
  }
}